// Round 1
// baseline (739.160 us; speedup 1.0000x reference)
//
#include <hip/hip_runtime.h>
#include <hip/hip_bf16.h>

// Problem constants
constexpr int BQ = 512, CQ = 200, EQ = 128, CV = 384, KD = 384;
constexpr int M = BQ * CQ;          // 102400 rows
constexpr int BM = 128, BN = 128, BK = 64;
constexpr int LD = BK + 8;          // LDS row stride (bf16 elems): 72 -> 144B, 16B aligned, 2-way bank alias (free)

using frag  = __attribute__((ext_vector_type(8))) short;  // 8 bf16
using facc  = __attribute__((ext_vector_type(4))) float;  // 4 f32 acc

// round-to-nearest-even f32 -> bf16 bits (inputs are finite; no NaN handling needed)
__device__ __forceinline__ short f2b(float f) {
    unsigned int u = __float_as_uint(f);
    u = (u + 0x7fffu + ((u >> 16) & 1u)) >> 16;
    return (short)u;
}

__device__ __forceinline__ float tanh_fast(float x) {
    // tanh(x) = 1 - 2/(e^{2x}+1); rel err ~1e-7 at our |x| <~ 1 scale
    float e = __expf(2.0f * x);
    return 1.0f - 2.0f * __builtin_amdgcn_rcpf(e + 1.0f);
}

// K1: fused gather -> bf16 GEMM (h = tanh(ctx @ W^T)) -> h to ws (bf16), partial scores via atomics
__global__ __launch_bounds__(256) void c2v_gemm_h(
    const int* __restrict__ starts, const int* __restrict__ paths, const int* __restrict__ ends,
    const float* __restrict__ node_emb, const float* __restrict__ path_emb,
    const float* __restrict__ W, const float* __restrict__ a,
    short* __restrict__ h_out, float* __restrict__ scores)
{
    __shared__ short As[BM * LD];
    __shared__ short Bs[BN * LD];

    const int tid   = threadIdx.x;
    const int bid   = blockIdx.x;
    const int ntile = bid % 3;             // 3 N-tiles (384/128)
    const int mtile = bid / 3;             // 800 M-tiles
    const int m0 = mtile * BM;
    const int n0 = ntile * BN;

    // staging coords: 2 threads per row, 32 f32 each
    const int srow  = tid >> 1;            // 0..127
    const int shalf = tid & 1;             // k sub-half 0..1

    // MFMA coords
    const int wave = tid >> 6;
    const int lane = tid & 63;
    const int wm = (wave >> 1) * 64;
    const int wn = (wave & 1) * 64;
    const int l15  = lane & 15;
    const int quad = lane >> 4;

    facc acc[4][4];
#pragma unroll
    for (int i = 0; i < 4; ++i)
#pragma unroll
        for (int j = 0; j < 4; ++j) acc[i][j] = (facc){0.f, 0.f, 0.f, 0.f};

    const int mrow = m0 + srow;
    const int s_idx = starts[mrow];
    const int p_idx = paths[mrow];
    const int e_idx = ends[mrow];

#pragma unroll
    for (int kc = 0; kc < 6; ++kc) {
        __syncthreads();   // protect LDS from previous iteration's readers
        // ---- stage A chunk: rows m0..m0+127, k in [kc*64, kc*64+64), gathered
        {
            const int seg = kc >> 1;
            int idx = (seg == 0) ? s_idx : ((seg == 1) ? p_idx : e_idx);
            const float* tab = (seg == 1) ? path_emb : node_emb;
            const float4* s4 = (const float4*)(tab + (size_t)idx * EQ + (kc & 1) * 64 + shalf * 32);
            short* dst = &As[srow * LD + shalf * 32];
#pragma unroll
            for (int u = 0; u < 4; ++u) {
                float4 v0 = s4[2 * u], v1 = s4[2 * u + 1];
                frag w;
                w[0] = f2b(v0.x); w[1] = f2b(v0.y); w[2] = f2b(v0.z); w[3] = f2b(v0.w);
                w[4] = f2b(v1.x); w[5] = f2b(v1.y); w[6] = f2b(v1.z); w[7] = f2b(v1.w);
                *(frag*)(dst + u * 8) = w;
            }
        }
        // ---- stage W chunk: rows n0..n0+127 of W[v][k]
        {
            const float4* s4 = (const float4*)(W + (size_t)(n0 + srow) * KD + kc * 64 + shalf * 32);
            short* dst = &Bs[srow * LD + shalf * 32];
#pragma unroll
            for (int u = 0; u < 4; ++u) {
                float4 v0 = s4[2 * u], v1 = s4[2 * u + 1];
                frag w;
                w[0] = f2b(v0.x); w[1] = f2b(v0.y); w[2] = f2b(v0.z); w[3] = f2b(v0.w);
                w[4] = f2b(v1.x); w[5] = f2b(v1.y); w[6] = f2b(v1.z); w[7] = f2b(v1.w);
                *(frag*)(dst + u * 8) = w;
            }
        }
        __syncthreads();
        // ---- MFMA: two k-steps of 32
#pragma unroll
        for (int ks = 0; ks < 2; ++ks) {
            const int ko = ks * 32 + quad * 8;
            frag af[4], bf[4];
#pragma unroll
            for (int i = 0; i < 4; ++i)
                af[i] = *(const frag*)&As[(wm + i * 16 + l15) * LD + ko];
#pragma unroll
            for (int j = 0; j < 4; ++j)
                bf[j] = *(const frag*)&Bs[(wn + j * 16 + l15) * LD + ko];
#pragma unroll
            for (int i = 0; i < 4; ++i)
#pragma unroll
                for (int j = 0; j < 4; ++j)
                    acc[i][j] = __builtin_amdgcn_mfma_f32_16x16x32_bf16(af[i], bf[j], acc[i][j], 0, 0, 0);
        }
    }

    // ---- epilogue: tanh, store h (bf16), reduce scores
    float av[4];
#pragma unroll
    for (int j = 0; j < 4; ++j) av[j] = a[n0 + wn + j * 16 + l15];

#pragma unroll
    for (int i = 0; i < 4; ++i) {
        float sc[4] = {0.f, 0.f, 0.f, 0.f};
#pragma unroll
        for (int j = 0; j < 4; ++j) {
            const int col = n0 + wn + j * 16 + l15;
#pragma unroll
            for (int r = 0; r < 4; ++r) {
                const int row = m0 + wm + i * 16 + quad * 4 + r;
                float hv = tanh_fast(acc[i][j][r]);
                h_out[(size_t)row * CV + col] = f2b(hv);
                sc[r] = fmaf(hv, av[j], sc[r]);
            }
        }
#pragma unroll
        for (int r = 0; r < 4; ++r) {
            float v = sc[r];
            v += __shfl_xor(v, 1);
            v += __shfl_xor(v, 2);
            v += __shfl_xor(v, 4);
            v += __shfl_xor(v, 8);
            if (l15 == 0)
                atomicAdd(&scores[m0 + wm + i * 16 + quad * 4 + r], v);
        }
    }
}

// K2: per-batch softmax over C=200 + attention-weighted sum of h -> out[b][v]
__global__ __launch_bounds__(256) void c2v_attn_out(
    const float* __restrict__ scores, const short* __restrict__ h,
    float* __restrict__ out)
{
    __shared__ float attn_s[CQ];
    __shared__ float wred[4];

    const int b = blockIdx.x;
    const int t = threadIdx.x;
    const int lane = t & 63, wv = t >> 6;

    float s = (t < CQ) ? scores[b * CQ + t] : -1e30f;
    float m = s;
#pragma unroll
    for (int o = 32; o; o >>= 1) m = fmaxf(m, __shfl_xor(m, o));
    if (lane == 0) wred[wv] = m;
    __syncthreads();
    const float gm = fmaxf(fmaxf(wred[0], wred[1]), fmaxf(wred[2], wred[3]));
    __syncthreads();

    float e = (t < CQ) ? __expf(s - gm) : 0.0f;
    float sum = e;
#pragma unroll
    for (int o = 32; o; o >>= 1) sum += __shfl_xor(sum, o);
    if (lane == 0) wred[wv] = sum;
    __syncthreads();
    const float gs = wred[0] + wred[1] + wred[2] + wred[3];
    if (t < CQ) attn_s[t] = e / gs;
    __syncthreads();

    if (t < 192) {
        const short* hp = h + (size_t)b * CQ * CV + 2 * t;
        float a0 = 0.f, a1 = 0.f;
#pragma unroll 4
        for (int c = 0; c < CQ; ++c) {
            unsigned int u = *(const unsigned int*)hp;
            hp += CV;
            const float w = attn_s[c];
            a0 = fmaf(__uint_as_float(u << 16), w, a0);
            a1 = fmaf(__uint_as_float(u & 0xffff0000u), w, a1);
        }
        out[b * CV + 2 * t]     = a0;
        out[b * CV + 2 * t + 1] = a1;
    }
}

extern "C" void kernel_launch(void* const* d_in, const int* in_sizes, int n_in,
                              void* d_out, int out_size, void* d_ws, size_t ws_size,
                              hipStream_t stream) {
    const int*   starts   = (const int*)d_in[0];
    const int*   paths    = (const int*)d_in[1];
    const int*   ends     = (const int*)d_in[2];
    // d_in[3] = masks: unused (as in reference)
    const float* node_emb = (const float*)d_in[4];
    const float* path_emb = (const float*)d_in[5];
    const float* W        = (const float*)d_in[6];
    const float* a        = (const float*)d_in[7];
    float* out = (float*)d_out;

    // ws layout: h (bf16, M*CV) | scores (f32, M)
    short* h_ws = (short*)d_ws;
    float* scores = (float*)((char*)d_ws + (size_t)M * CV * sizeof(short));

    hipMemsetAsync(scores, 0, (size_t)M * sizeof(float), stream);

    c2v_gemm_h<<<(M / BM) * (CV / BN), 256, 0, stream>>>(
        starts, paths, ends, node_emb, path_emb, W, a, h_ws, scores);

    c2v_attn_out<<<BQ, 256, 0, stream>>>(scores, h_ws, out);
}

// Round 2
// 681.783 us; speedup vs baseline: 1.0842x; 1.0842x over previous
//
#include <hip/hip_runtime.h>
#include <hip/hip_bf16.h>

// Problem constants
constexpr int BQ = 512, CQ = 200, EQ = 128, CV = 384, KD = 384;
constexpr int M = BQ * CQ;          // 102400 rows
constexpr int BM = 128, BN = 128;   // GEMM tile; BK = 64 bf16 = 128 B rows in LDS

using frag  = __attribute__((ext_vector_type(8))) short;  // 8 bf16 (4 VGPRs)
using facc  = __attribute__((ext_vector_type(4))) float;  // 4 f32 acc

// round-to-nearest-even f32 -> bf16 bits (inputs finite)
__device__ __forceinline__ short f2b(float f) {
    unsigned int u = __float_as_uint(f);
    u = (u + 0x7fffu + ((u >> 16) & 1u)) >> 16;
    return (short)u;
}
__device__ __forceinline__ unsigned pack2(float lo, float hi) {
    return (unsigned)(unsigned short)f2b(lo) | ((unsigned)(unsigned short)f2b(hi) << 16);
}

__device__ __forceinline__ float tanh_fast(float x) {
    float e = __expf(2.0f * x);
    return 1.0f - 2.0f * __builtin_amdgcn_rcpf(e + 1.0f);
}

// async global->LDS, 16B per lane; LDS dst is wave-uniform base + lane*16
__device__ __forceinline__ void async16(const void* g, void* l) {
    __builtin_amdgcn_global_load_lds(
        (const __attribute__((address_space(1))) void*)g,
        (__attribute__((address_space(3))) void*)l, 16, 0, 0);
}

// ---- K0a: W f32 -> bf16 ----
__global__ __launch_bounds__(256) void conv_w(const float* __restrict__ W, short* __restrict__ Wb) {
    int i = (blockIdx.x * 256 + threadIdx.x) * 4;
    float4 v = *(const float4*)(W + i);
    uint2 o;
    o.x = pack2(v.x, v.y);
    o.y = pack2(v.z, v.w);
    *(uint2*)(Wb + i) = o;
}

// ---- K0b: gather + convert -> ctx_bf16 [M, 384] (s|p|e), one wave per row ----
__global__ __launch_bounds__(256) void build_ctx(
    const int* __restrict__ starts, const int* __restrict__ paths, const int* __restrict__ ends,
    const float* __restrict__ node_emb, const float* __restrict__ path_emb,
    short* __restrict__ ctx)
{
    const int wave = threadIdx.x >> 6, lane = threadIdx.x & 63;
    const int row = blockIdx.x * 4 + wave;
    const int si = starts[row], pi = paths[row], ei = ends[row];
    unsigned* dst = (unsigned*)(ctx + (size_t)row * KD);

    float2 v;
    v = ((const float2*)(node_emb + (size_t)si * EQ))[lane];
    dst[lane] = pack2(v.x, v.y);
    v = ((const float2*)(path_emb + (size_t)pi * EQ))[lane];
    dst[64 + lane] = pack2(v.x, v.y);
    v = ((const float2*)(node_emb + (size_t)ei * EQ))[lane];
    dst[128 + lane] = pack2(v.x, v.y);
}

// ---- K1: m97-style GEMM h = tanh(ctx @ Wb^T); h (bf16) + 6-slab score partials ----
__global__ __launch_bounds__(256) void gemm_h(
    const short* __restrict__ ctx, const short* __restrict__ Wb, const float* __restrict__ a,
    short* __restrict__ h_out, float* __restrict__ scores6)
{
    __shared__ short As[BM * 64];   // 128 rows x 128 B, XOR-swizzled 16B columns
    __shared__ short Bs[BN * 64];

    const int tid = threadIdx.x, bid = blockIdx.x;
    const int ntile = bid % 3, mtile = bid / 3;
    const int m0 = mtile * BM, n0 = ntile * BN;

    const int wave = tid >> 6, lane = tid & 63;
    const int wm = (wave >> 1) * 64, wn = (wave & 1) * 64;
    const int l15 = lane & 15, quad = lane >> 4;

    // staging: within a 1KB instr, lane covers row (lane>>3), 16B col (lane&7);
    // content swizzle: global col16 = (lane&7) ^ (lane>>3 & 7)
    const int sr = lane >> 3;                    // 0..7 row-in-group
    const int sc = ((lane & 7) ^ (sr & 7)) * 16; // swizzled byte offset in 128B row

    facc acc[4][4];
#pragma unroll
    for (int i = 0; i < 4; ++i)
#pragma unroll
        for (int j = 0; j < 4; ++j) acc[i][j] = (facc){0.f, 0.f, 0.f, 0.f};

    const char* cA = (const char*)ctx;
    const char* cB = (const char*)Wb;

#pragma unroll
    for (int kc = 0; kc < 6; ++kc) {
        __syncthreads();   // protect LDS from previous iteration's readers
#pragma unroll
        for (int t = 0; t < 4; ++t) {
            const int r = wave * 32 + t * 8 + sr;
            async16(cA + (((size_t)(m0 + r) * KD + kc * 64) << 1) + sc,
                    &As[(wave * 32 + t * 8) * 64]);
            async16(cB + (((size_t)(n0 + r) * KD + kc * 64) << 1) + sc,
                    &Bs[(wave * 32 + t * 8) * 64]);
        }
        __syncthreads();   // drains vmcnt for the async copies

#pragma unroll
        for (int ks = 0; ks < 2; ++ks) {
            frag af[4], bf[4];
            const int c16 = ks * 4 + quad;              // logical 16B col within 128B row
            const int co = (c16 ^ (l15 & 7)) * 8;       // swizzled short offset
#pragma unroll
            for (int i = 0; i < 4; ++i)
                af[i] = *(const frag*)&As[(wm + i * 16 + l15) * 64 + co];
#pragma unroll
            for (int j = 0; j < 4; ++j)
                bf[j] = *(const frag*)&Bs[(wn + j * 16 + l15) * 64 + co];
#pragma unroll
            for (int i = 0; i < 4; ++i)
#pragma unroll
                for (int j = 0; j < 4; ++j)
                    acc[i][j] = __builtin_amdgcn_mfma_f32_16x16x32_bf16(af[i], bf[j], acc[i][j], 0, 0, 0);
        }
    }

    // ---- epilogue: tanh, store h bf16, per-row score partial -> slab (no atomics)
    float av[4];
#pragma unroll
    for (int j = 0; j < 4; ++j) av[j] = a[n0 + wn + j * 16 + l15];
    const int slab = ntile * 2 + (wn >> 6);

#pragma unroll
    for (int i = 0; i < 4; ++i) {
        float sct[4] = {0.f, 0.f, 0.f, 0.f};
#pragma unroll
        for (int j = 0; j < 4; ++j) {
            const int col = n0 + wn + j * 16 + l15;
#pragma unroll
            for (int r = 0; r < 4; ++r) {
                const int row = m0 + wm + i * 16 + quad * 4 + r;
                float hv = tanh_fast(acc[i][j][r]);
                h_out[(size_t)row * CV + col] = f2b(hv);
                sct[r] = fmaf(hv, av[j], sct[r]);
            }
        }
#pragma unroll
        for (int r = 0; r < 4; ++r) {
            float v = sct[r];
            v += __shfl_xor(v, 1);
            v += __shfl_xor(v, 2);
            v += __shfl_xor(v, 4);
            v += __shfl_xor(v, 8);
            if (l15 == 0)
                scores6[(size_t)slab * M + m0 + wm + i * 16 + quad * 4 + r] = v;
        }
    }
}

// ---- K2: per-batch softmax over C=200 + attention-weighted sum -> out[b][v] ----
__global__ __launch_bounds__(256) void c2v_attn_out(
    const float* __restrict__ scores6, const short* __restrict__ h,
    float* __restrict__ out)
{
    __shared__ float attn_s[CQ];
    __shared__ float wred[4];

    const int b = blockIdx.x;
    const int t = threadIdx.x;
    const int lane = t & 63, wv = t >> 6;

    float s = -1e30f;
    if (t < CQ) {
        const int r = b * CQ + t;
        s = scores6[r] + scores6[M + r] + scores6[2 * (size_t)M + r]
          + scores6[3 * (size_t)M + r] + scores6[4 * (size_t)M + r] + scores6[5 * (size_t)M + r];
    }
    float m = s;
#pragma unroll
    for (int o = 32; o; o >>= 1) m = fmaxf(m, __shfl_xor(m, o));
    if (lane == 0) wred[wv] = m;
    __syncthreads();
    const float gm = fmaxf(fmaxf(wred[0], wred[1]), fmaxf(wred[2], wred[3]));
    __syncthreads();

    float e = (t < CQ) ? __expf(s - gm) : 0.0f;
    float sum = e;
#pragma unroll
    for (int o = 32; o; o >>= 1) sum += __shfl_xor(sum, o);
    if (lane == 0) wred[wv] = sum;
    __syncthreads();
    const float gs = wred[0] + wred[1] + wred[2] + wred[3];
    if (t < CQ) attn_s[t] = e / gs;
    __syncthreads();

    if (t < 192) {
        const short* hp = h + (size_t)b * CQ * CV + 2 * t;
        float a0 = 0.f, a1 = 0.f;
#pragma unroll 4
        for (int c = 0; c < CQ; ++c) {
            unsigned int u = *(const unsigned int*)hp;
            hp += CV;
            const float w = attn_s[c];
            a0 = fmaf(__uint_as_float(u << 16), w, a0);
            a1 = fmaf(__uint_as_float(u & 0xffff0000u), w, a1);
        }
        out[b * CV + 2 * t]     = a0;
        out[b * CV + 2 * t + 1] = a1;
    }
}

extern "C" void kernel_launch(void* const* d_in, const int* in_sizes, int n_in,
                              void* d_out, int out_size, void* d_ws, size_t ws_size,
                              hipStream_t stream) {
    const int*   starts   = (const int*)d_in[0];
    const int*   paths    = (const int*)d_in[1];
    const int*   ends     = (const int*)d_in[2];
    // d_in[3] = masks: unused (as in reference)
    const float* node_emb = (const float*)d_in[4];
    const float* path_emb = (const float*)d_in[5];
    const float* W        = (const float*)d_in[6];
    const float* a        = (const float*)d_in[7];
    float* out = (float*)d_out;

    // ws layout: h bf16 [M*CV] | ctx bf16 [M*KD] | Wb bf16 [CV*KD] | scores6 f32 [6*M]
    char* p = (char*)d_ws;
    short* h_ws   = (short*)p;  p += (size_t)M * CV * sizeof(short);
    short* ctx_ws = (short*)p;  p += (size_t)M * KD * sizeof(short);
    short* Wb     = (short*)p;  p += (size_t)CV * KD * sizeof(short);
    float* scores6 = (float*)p;

    conv_w<<<(CV * KD) / 1024, 256, 0, stream>>>(W, Wb);
    build_ctx<<<M / 4, 256, 0, stream>>>(starts, paths, ends, node_emb, path_emb, ctx_ws);
    gemm_h<<<(M / BM) * 3, 256, 0, stream>>>(ctx_ws, Wb, a, h_ws, scores6);
    c2v_attn_out<<<BQ, 256, 0, stream>>>(scores6, h_ws, out);
}